// Round 3
// baseline (1145.822 us; speedup 1.0000x reference)
//
#include <hip/hip_runtime.h>
#include <cstddef>

#define S 512
#define SHIFT_HW 18      // 512*512 = 1<<18
#define NCOL 16384

// workspace layout (float offsets)
#define QB_OFF 0ull
#define KB_OFF 25165824ull
#define VB_OFF 50331648ull
#define G_OFF  75497472ull
#define SQ_OFF 75644928ull
#define SK_OFF 75646464ull
#define A_OFF  75648000ull
// total 75795456 floats = 303.2 MB

#define QS_STRIDE 327    // odd (7 mod 32): depthwise reads <=2-way bank aliasing

// ---------------------------------------------------------------------------
// K1 v2.1: fused 1x1 qkv conv + 3x3 depthwise (zero pad) + scatter to blocked
// layout. grid (32,32,2), block 384. 16x16 output tile, 18x18 halo.
// Depthwise: thread = (channel, row): sliding-window 3x3, float4 stores.
// FIX vs v2: dws was [432], must be 144*9 = [1296] -> LDS OOB trap killed K1.
// ---------------------------------------------------------------------------
__global__ __launch_bounds__(384) void k1_qkv_dw(
    const float* __restrict__ x, const float* __restrict__ qkv_w,
    const float* __restrict__ dw_w,
    float* __restrict__ qb, float* __restrict__ kb, float* __restrict__ vb)
{
  const int t = threadIdx.x;
  const int b = blockIdx.z;
  const int W0 = blockIdx.x * 16, H0 = blockIdx.y * 16;
  __shared__ float qs[24 * QS_STRIDE];   // 31.4 KB: 24-ch group over 18x18 halo
  __shared__ float dws[1296];            // all depthwise weights (144 ch x 9)

  for (int i = t; i < 1296; i += 384) dws[i] = dw_w[i];

  // per-thread halo pixel, x channels held in registers across all 6 groups
  float xv[48];
  const int p  = t;
  const int hy = p / 18, hx = p % 18;            // valid for t<324
  const int Hg = H0 - 1 + hy, Wg = W0 - 1 + hx;
  const bool inb = (t < 324) && (Hg >= 0) && (Hg < S) && (Wg >= 0) && (Wg < S);
  const float* xb = x + ((size_t)b * 48 << SHIFT_HW) + (inb ? ((Hg << 9) + Wg) : 0);
  #pragma unroll
  for (int ic = 0; ic < 48; ++ic) {
    float v = 0.0f;
    if (inb) v = xb[(size_t)ic << SHIFT_HW];
    xv[ic] = v;
  }

  // depthwise task: thread owns (ch, output row y), all 16 x-positions
  const int ch = t >> 4;                 // 0..23 (channel within group)
  const int y  = t & 15;                 // output row within tile
  const int nb = (blockIdx.y * 4 + (y >> 2)) * 128 + blockIdx.x * 4;
  const float* qrow = qs + ch * QS_STRIDE + y * 18;  // halo rows y..y+2

  __syncthreads();   // dws ready

  #pragma unroll 1
  for (int g = 0; g < 6; ++g) {
    // ---- pointwise GEMM: 24 output channels for this group, halo pixels ----
    if (t < 324) {
      const float* wgp = qkv_w + g * 24 * 48;   // uniform -> s_loads
      #pragma unroll
      for (int oc = 0; oc < 24; oc += 2) {
        float a0 = 0.f, a1 = 0.f;
        #pragma unroll
        for (int ic = 0; ic < 48; ++ic) {
          a0 += wgp[oc * 48 + ic]       * xv[ic];
          a1 += wgp[(oc + 1) * 48 + ic] * xv[ic];
        }
        qs[oc * QS_STRIDE + p]       = a0;
        qs[(oc + 1) * QS_STRIDE + p] = a1;
      }
    }
    __syncthreads();

    // ---- depthwise 3x3 (sliding window) + float4 scatter ----
    const int tensor = g >> 1;            // 0=q,1=k,2=v
    const int chbase = (g & 1) * 24;
    const int chg  = chbase + ch;         // channel within tensor
    const int head = chg / 6, c = chg - 6 * head;
    float* dst = (tensor == 0) ? qb : (tensor == 1) ? kb : vb;
    float* dstp = dst + ((size_t)((b * 8 + head) * 96 + c * 16 + (y & 3) * 4)) * NCOL + nb;
    const float* wp = dws + (tensor * 48 + chg) * 9;
    float w0 = wp[0], w1 = wp[1], w2 = wp[2];
    float w3 = wp[3], w4 = wp[4], w5 = wp[5];
    float w6 = wp[6], w7 = wp[7], w8 = wp[8];

    float out[16];
    float p00 = qrow[0], p01 = qrow[18], p02 = qrow[36];
    float p10 = qrow[1], p11 = qrow[19], p12 = qrow[37];
    #pragma unroll
    for (int xq = 0; xq < 16; ++xq) {
      const float n0 = qrow[xq + 2];
      const float n1 = qrow[xq + 20];
      const float n2 = qrow[xq + 38];
      out[xq] = w0 * p00 + w1 * p10 + w2 * n0
              + w3 * p01 + w4 * p11 + w5 * n1
              + w6 * p02 + w7 * p12 + w8 * n2;
      p00 = p10; p01 = p11; p02 = p12;
      p10 = n0;  p11 = n1;  p12 = n2;
    }
    #pragma unroll
    for (int wl = 0; wl < 4; ++wl) {
      float4 v4 = {out[wl], out[wl + 4], out[wl + 8], out[wl + 12]};
      *(float4*)(dstp + (size_t)wl * NCOL) = v4;
    }
    __syncthreads();
  }
}

// ---------------------------------------------------------------------------
// K3: raw Gram G[bh] = q@k^T (96x96 over K=16384) + row sum-squares, atomics.
// grid (32 chunks of 512 cols, 16 bh), block 256.
// ---------------------------------------------------------------------------
__global__ __launch_bounds__(256) void k3_gram(
    const float* __restrict__ qb, const float* __restrict__ kb,
    float* __restrict__ G, float* __restrict__ sq, float* __restrict__ sk)
{
  const int t  = threadIdx.x;
  const int bh = blockIdx.y;
  const int n0 = blockIdx.x * 512;
  __shared__ float qt[96 * 66];   // stride 66: 2-way bank aliasing only (free)
  __shared__ float kt[96 * 66];
  const int ti = t >> 4, tj = t & 15;
  float acc[6][6];
  #pragma unroll
  for (int r = 0; r < 6; ++r)
    #pragma unroll
    for (int s_ = 0; s_ < 6; ++s_) acc[r][s_] = 0.f;
  float ss = 0.f;
  const float* qbase = qb + (size_t)bh * 96 * NCOL;
  const float* kbase = kb + (size_t)bh * 96 * NCOL;
  const int srow = (t < 96) ? t : (t - 96);

  #pragma unroll 1
  for (int st = 0; st < 8; ++st) {
    const int nb = n0 + st * 64;
    __syncthreads();
    #pragma unroll
    for (int r = 0; r < 12; ++r) {          // 96x64 tile as float2 per tensor
      const int idx = r * 256 + t;
      const int row = idx >> 5, c2 = (idx & 31) * 2;
      const float2 qv = *(const float2*)(qbase + (size_t)row * NCOL + nb + c2);
      const float2 kv = *(const float2*)(kbase + (size_t)row * NCOL + nb + c2);
      *(float2*)(qt + row * 66 + c2) = qv;
      *(float2*)(kt + row * 66 + c2) = kv;
    }
    __syncthreads();
    #pragma unroll 2
    for (int nn = 0; nn < 64; nn += 2) {
      float2 qv[6], kv[6];
      #pragma unroll
      for (int r = 0; r < 6; ++r)  qv[r]  = *(const float2*)(qt + (ti * 6 + r) * 66 + nn);
      #pragma unroll
      for (int s_ = 0; s_ < 6; ++s_) kv[s_] = *(const float2*)(kt + (tj * 6 + s_) * 66 + nn);
      #pragma unroll
      for (int r = 0; r < 6; ++r)
        #pragma unroll
        for (int s_ = 0; s_ < 6; ++s_)
          acc[r][s_] += qv[r].x * kv[s_].x + qv[r].y * kv[s_].y;
    }
    if (t < 192) {                          // sum-squares for norms
      const float* base = (t < 96) ? qt : kt;
      float s2 = 0.f;
      #pragma unroll 4
      for (int nn = 0; nn < 64; ++nn) {
        const float v = base[srow * 66 + nn];
        s2 += v * v;
      }
      ss += s2;
    }
  }
  float* Gb = G + (size_t)bh * 9216;
  #pragma unroll
  for (int r = 0; r < 6; ++r)
    #pragma unroll
    for (int s_ = 0; s_ < 6; ++s_)
      atomicAdd(Gb + (ti * 6 + r) * 96 + (tj * 6 + s_), acc[r][s_]);
  if (t < 96)       atomicAdd(sq + bh * 96 + t,        ss);
  else if (t < 192) atomicAdd(sk + bh * 96 + (t - 96), ss);
}

// ---------------------------------------------------------------------------
// K4: normalize logits + per-head temperature + row softmax (96 wide).
// grid (96 rows, 16 bh), block 128.
// ---------------------------------------------------------------------------
__global__ __launch_bounds__(128) void k4_softmax(
    const float* __restrict__ G, const float* __restrict__ sq,
    const float* __restrict__ sk, const float* __restrict__ temp,
    float* __restrict__ A)
{
  const int i  = blockIdx.x;
  const int bh = blockIdx.y;
  const int h  = bh & 7;
  const int t  = threadIdx.x;
  __shared__ float red[128];

  const float nq    = fmaxf(sqrtf(sq[bh * 96 + i]), 1e-12f);
  const float scale = temp[h] / nq;
  float logit = 0.f, val = -1e30f;
  if (t < 96) {
    const float nk = fmaxf(sqrtf(sk[bh * 96 + t]), 1e-12f);
    logit = G[(size_t)bh * 9216 + i * 96 + t] * scale / nk;
    val = logit;
  }
  red[t] = val; __syncthreads();
  #pragma unroll
  for (int o = 64; o > 0; o >>= 1) {
    if (t < o) red[t] = fmaxf(red[t], red[t + o]);
    __syncthreads();
  }
  const float m = red[0]; __syncthreads();
  const float e = (t < 96) ? __expf(logit - m) : 0.f;
  red[t] = e; __syncthreads();
  #pragma unroll
  for (int o = 64; o > 0; o >>= 1) {
    if (t < o) red[t] += red[t + o];
    __syncthreads();
  }
  const float ssum = red[0];
  if (t < 96) A[(size_t)bh * 9216 + i * 96 + t] = e / ssum;
}

// ---------------------------------------------------------------------------
// K5: out = proj( from_blocks( A @ v ) ). One block = 16 attention columns
// (fixed hh, 16 consecutive ww) => output tile 4 rows x 64 cols x 48 ch.
// grid (8 wgrp, 128 hh, 2 b), block 256.
// ---------------------------------------------------------------------------
__global__ __launch_bounds__(256) void k5_av_proj(
    const float* __restrict__ vb, const float* __restrict__ A,
    const float* __restrict__ pw, float* __restrict__ out)
{
  const int t  = threadIdx.x;
  const int wg = blockIdx.x, hh = blockIdx.y, b = blockIdx.z;
  const int n0 = hh * 128 + wg * 16;
  __shared__ float vt[768 * 16];   // 49.2 KB: v[h][j][nl]
  __shared__ float ao[48 * 256];   // 49.2 KB: attn-out [ic][p][ww]

  // load v tile (float4, fully coalesced)
  #pragma unroll
  for (int r = 0; r < 12; ++r) {
    const int i4 = r * 256 + t;
    const int hj = i4 >> 2, nq = i4 & 3;
    const float4 v = *(const float4*)(vb + ((size_t)(b * 768 + hj) << 14) + n0 + nq * 4);
    *(float4*)(vt + hj * 16 + nq * 4) = v;
  }
  __syncthreads();

  // A @ v : per task 2 rows x 4 cols (8 FMA per ds_read_b128, broadcast)
  #pragma unroll 1
  for (int r = 0; r < 6; ++r) {
    const int task = r * 256 + t;           // h(8) x ip(48) x n4(4) = 1536
    const int n4 = task & 3;
    const int ip = (task >> 2) % 48;
    const int h  = task / 192;
    const int i0 = ip * 2;
    const float* arow0 = A + (size_t)((b * 8 + h) * 96 + i0) * 96;
    const float* arow1 = arow0 + 96;
    const float* vp = vt + h * 1536 + n4 * 4;
    float4 a0 = {0, 0, 0, 0}, a1 = {0, 0, 0, 0};
    #pragma unroll 4
    for (int j = 0; j < 96; ++j) {
      const float4 v4 = *(const float4*)(vp + j * 16);
      const float w0 = arow0[j], w1 = arow1[j];
      a0.x += w0 * v4.x; a0.y += w0 * v4.y; a0.z += w0 * v4.z; a0.w += w0 * v4.w;
      a1.x += w1 * v4.x; a1.y += w1 * v4.y; a1.z += w1 * v4.z; a1.w += w1 * v4.w;
    }
    const int c0 = i0 >> 4, p0 = i0 & 15;
    *(float4*)(ao + ((h * 6 + c0) * 16 + p0) * 16 + n4 * 4) = a0;
    const int i1 = i0 + 1;
    const int c1 = i1 >> 4, p1 = i1 & 15;
    *(float4*)(ao + ((h * 6 + c1) * 16 + p1) * 16 + n4 * 4) = a1;
  }
  __syncthreads();

  // proj 1x1: thread owns one output pixel across all 48 output channels
  const int xl = t & 63, ph = t >> 6;
  const int p  = ph * 4 + (xl & 3);
  const int wwl = xl >> 2;
  float sv[48];
  #pragma unroll
  for (int ic = 0; ic < 48; ++ic) sv[ic] = ao[(ic * 16 + p) * 16 + wwl];
  const int H = hh * 4 + ph;
  const int Wp = wg * 64 + xl;
  float* outp = out + ((size_t)b * 48 << SHIFT_HW) + (H << 9) + Wp;
  #pragma unroll 1
  for (int oc = 0; oc < 48; oc += 2) {
    float acc0 = 0.f, acc1 = 0.f;
    #pragma unroll
    for (int ic = 0; ic < 48; ++ic) {
      acc0 += pw[oc * 48 + ic]       * sv[ic];   // uniform -> s_loads
      acc1 += pw[(oc + 1) * 48 + ic] * sv[ic];
    }
    outp[(size_t)oc << SHIFT_HW]       = acc0;
    outp[(size_t)(oc + 1) << SHIFT_HW] = acc1;
  }
}

// ---------------------------------------------------------------------------
extern "C" void kernel_launch(void* const* d_in, const int* in_sizes, int n_in,
                              void* d_out, int out_size, void* d_ws, size_t ws_size,
                              hipStream_t stream) {
  const float* x      = (const float*)d_in[0];
  const float* qkv_w  = (const float*)d_in[1];
  const float* dw_w   = (const float*)d_in[2];
  const float* proj_w = (const float*)d_in[3];
  const float* temp   = (const float*)d_in[4];
  float* ws = (float*)d_ws;
  float* qb = ws + QB_OFF;
  float* kb = ws + KB_OFF;
  float* vb = ws + VB_OFF;
  float* G  = ws + G_OFF;
  float* sq = ws + SQ_OFF;
  float* sk = ws + SK_OFF;
  float* A  = ws + A_OFF;

  // zero G + sq + sk (contiguous region); A is fully overwritten by k4
  hipMemsetAsync(G, 0, (size_t)(147456 + 3072) * sizeof(float), stream);

  k1_qkv_dw<<<dim3(32, 32, 2), 384, 0, stream>>>(x, qkv_w, dw_w, qb, kb, vb);
  k3_gram<<<dim3(32, 16), 256, 0, stream>>>(qb, kb, G, sq, sk);
  k4_softmax<<<dim3(96, 16), 128, 0, stream>>>(G, sq, sk, temp, A);
  k5_av_proj<<<dim3(8, 128, 2), 256, 0, stream>>>(vb, A, proj_w, (float*)d_out);
}

// Round 4
// 1001.456 us; speedup vs baseline: 1.1442x; 1.1442x over previous
//
#include <hip/hip_runtime.h>
#include <cstddef>

#define S 512
#define SHIFT_HW 18      // 512*512 = 1<<18
#define NCOL 16384

// workspace layout (float offsets). q/k/v are COLUMN-MAJOR blocked:
//   qb[bh][n][r], bh in [0,16), n in [0,16384), r in [0,96)
// so K1's stores (r contiguous) and K3/K5's tile loads (n-range contiguous)
// are both coalesced. Round-3 rocprof: row-major gave 2x WRITE_SIZE (partial
// line RMW) and capped K1 at 1.35 TB/s combined.
#define QB_OFF 0ull
#define KB_OFF 25165824ull
#define VB_OFF 50331648ull
#define G_OFF  75497472ull
#define SQ_OFF 75644928ull
#define SK_OFF 75646464ull
#define A_OFF  75648000ull

#define QS_STRIDE 327    // odd (7 mod 32): depthwise reads <=2-way bank aliasing

// ---------------------------------------------------------------------------
// K1 v3: fused 1x1 qkv conv + 3x3 depthwise (zero pad) + scatter to
// column-major blocked layout. grid (32,32,2), block 384. 16x16 tile.
// ---------------------------------------------------------------------------
__global__ __launch_bounds__(384) void k1_qkv_dw(
    const float* __restrict__ x, const float* __restrict__ qkv_w,
    const float* __restrict__ dw_w,
    float* __restrict__ qb, float* __restrict__ kb, float* __restrict__ vb)
{
  const int t = threadIdx.x;
  const int b = blockIdx.z;
  const int W0 = blockIdx.x * 16, H0 = blockIdx.y * 16;
  __shared__ float qs[24 * QS_STRIDE];   // 24-ch group over 18x18 halo
  __shared__ float dws[1296];            // all depthwise weights (144 ch x 9)

  for (int i = t; i < 1296; i += 384) dws[i] = dw_w[i];

  // per-thread halo pixel, x channels held in registers across all 6 groups
  float xv[48];
  const int p  = t;
  const int hy = p / 18, hx = p % 18;            // valid for t<324
  const int Hg = H0 - 1 + hy, Wg = W0 - 1 + hx;
  const bool inb = (t < 324) && (Hg >= 0) && (Hg < S) && (Wg >= 0) && (Wg < S);
  const float* xb = x + ((size_t)b * 48 << SHIFT_HW) + (inb ? ((Hg << 9) + Wg) : 0);
  #pragma unroll
  for (int ic = 0; ic < 48; ++ic) {
    float v = 0.0f;
    if (inb) v = xb[(size_t)ic << SHIFT_HW];
    xv[ic] = v;
  }

  // depthwise task: thread owns (ch, output row y), all 16 x-positions
  const int ch = t >> 4;                 // 0..23 (channel within group)
  const int y  = t & 15;                 // output row within tile
  const int nb = (blockIdx.y * 4 + (y >> 2)) * 128 + blockIdx.x * 4;
  const float* qrow = qs + ch * QS_STRIDE + y * 18;  // halo rows y..y+2

  __syncthreads();   // dws ready

  #pragma unroll 1
  for (int g = 0; g < 6; ++g) {
    // ---- pointwise GEMM: 24 output channels for this group, halo pixels ----
    if (t < 324) {
      const float* wgp = qkv_w + g * 24 * 48;   // uniform -> s_loads
      #pragma unroll
      for (int oc = 0; oc < 24; oc += 2) {
        float a0 = 0.f, a1 = 0.f;
        #pragma unroll
        for (int ic = 0; ic < 48; ++ic) {
          a0 += wgp[oc * 48 + ic]       * xv[ic];
          a1 += wgp[(oc + 1) * 48 + ic] * xv[ic];
        }
        qs[oc * QS_STRIDE + p]       = a0;
        qs[(oc + 1) * QS_STRIDE + p] = a1;
      }
    }
    __syncthreads();

    // ---- depthwise 3x3 (sliding window) + coalesced float4 stores ----
    // out[xq] -> n = nb + (xq>>2), r = c*16 + (y&3)*4 + (xq&3):
    // one float4 per n, r contiguous. A wave's 16B pieces tile 128-256B
    // contiguous segments -> fully dirtied lines, no RMW.
    const int tensor = g >> 1;            // 0=q,1=k,2=v
    const int chbase = (g & 1) * 24;
    const int chg  = chbase + ch;         // channel within tensor
    const int head = chg / 6, c = chg - 6 * head;
    float* dst = (tensor == 0) ? qb : (tensor == 1) ? kb : vb;
    float* dstp = dst + (size_t)((b * 8 + head) * 16384 + nb) * 96
                      + c * 16 + (y & 3) * 4;
    const float* wp = dws + (tensor * 48 + chg) * 9;
    const float w0 = wp[0], w1 = wp[1], w2 = wp[2];
    const float w3 = wp[3], w4 = wp[4], w5 = wp[5];
    const float w6 = wp[6], w7 = wp[7], w8 = wp[8];

    float p00 = qrow[0], p01 = qrow[18], p02 = qrow[36];
    float p10 = qrow[1], p11 = qrow[19], p12 = qrow[37];
    #pragma unroll
    for (int wl = 0; wl < 4; ++wl) {
      float o[4];
      #pragma unroll
      for (int u = 0; u < 4; ++u) {
        const int xq = wl * 4 + u;
        const float n0 = qrow[xq + 2];
        const float n1 = qrow[xq + 20];
        const float n2 = qrow[xq + 38];
        o[u] = w0 * p00 + w1 * p10 + w2 * n0
             + w3 * p01 + w4 * p11 + w5 * n1
             + w6 * p02 + w7 * p12 + w8 * n2;
        p00 = p10; p01 = p11; p02 = p12;
        p10 = n0;  p11 = n1;  p12 = n2;
      }
      float4 v4 = {o[0], o[1], o[2], o[3]};
      *(float4*)(dstp + (size_t)wl * 96) = v4;
    }
    __syncthreads();
  }
}

// ---------------------------------------------------------------------------
// K3 v2: Gram G[bh] = q@k^T (96x96, K=16384) + row sum-squares. Column-major
// input: tile load is a flat contiguous copy. grid (64 x 256-col chunks, 16).
// ---------------------------------------------------------------------------
__global__ __launch_bounds__(256) void k3_gram(
    const float* __restrict__ qb, const float* __restrict__ kb,
    float* __restrict__ G, float* __restrict__ sq, float* __restrict__ sk)
{
  const int t  = threadIdx.x;
  const int bh = blockIdx.y;
  const int n0 = blockIdx.x * 256;
  __shared__ float qt[6144];   // [64 n][96 r] flat
  __shared__ float kt[6144];
  const int ti = t >> 4, tj = t & 15;
  float acc[6][6];
  #pragma unroll
  for (int r = 0; r < 6; ++r)
    #pragma unroll
    for (int s_ = 0; s_ < 6; ++s_) acc[r][s_] = 0.f;
  float ss = 0.f;
  const float* qbase = qb + (size_t)bh * 16384 * 96;
  const float* kbase = kb + (size_t)bh * 16384 * 96;

  #pragma unroll 1
  for (int st = 0; st < 4; ++st) {
    __syncthreads();
    const float4* qsrc = (const float4*)(qbase + (size_t)(n0 + st * 64) * 96);
    const float4* ksrc = (const float4*)(kbase + (size_t)(n0 + st * 64) * 96);
    #pragma unroll
    for (int r = 0; r < 6; ++r) {
      const int f4 = r * 256 + t;
      ((float4*)qt)[f4] = qsrc[f4];
      ((float4*)kt)[f4] = ksrc[f4];
    }
    __syncthreads();
    #pragma unroll 2
    for (int nn = 0; nn < 64; ++nn) {
      const float* qr = qt + nn * 96 + ti * 6;
      const float* kr = kt + nn * 96 + tj * 6;
      const float2 q0 = *(const float2*)(qr);
      const float2 q1 = *(const float2*)(qr + 2);
      const float2 q2 = *(const float2*)(qr + 4);
      const float2 k0 = *(const float2*)(kr);
      const float2 k1 = *(const float2*)(kr + 2);
      const float2 k2 = *(const float2*)(kr + 4);
      const float qv[6] = {q0.x, q0.y, q1.x, q1.y, q2.x, q2.y};
      const float kv[6] = {k0.x, k0.y, k1.x, k1.y, k2.x, k2.y};
      #pragma unroll
      for (int r = 0; r < 6; ++r)
        #pragma unroll
        for (int s_ = 0; s_ < 6; ++s_)
          acc[r][s_] += qv[r] * kv[s_];
    }
    if (t < 192) {                          // sum-squares for norms
      const float* base = (t < 96) ? qt : kt;
      const int srow = (t < 96) ? t : (t - 96);
      float s2 = 0.f;
      #pragma unroll 8
      for (int nn = 0; nn < 64; ++nn) {
        const float v = base[nn * 96 + srow];
        s2 += v * v;
      }
      ss += s2;
    }
  }
  float* Gb = G + (size_t)bh * 9216;
  #pragma unroll
  for (int r = 0; r < 6; ++r)
    #pragma unroll
    for (int s_ = 0; s_ < 6; ++s_)
      atomicAdd(Gb + (ti * 6 + r) * 96 + (tj * 6 + s_), acc[r][s_]);
  if (t < 96)       atomicAdd(sq + bh * 96 + t,        ss);
  else if (t < 192) atomicAdd(sk + bh * 96 + (t - 96), ss);
}

// ---------------------------------------------------------------------------
// K4: normalize logits + per-head temperature + row softmax (96 wide).
// grid (96 rows, 16 bh), block 128.
// ---------------------------------------------------------------------------
__global__ __launch_bounds__(128) void k4_softmax(
    const float* __restrict__ G, const float* __restrict__ sq,
    const float* __restrict__ sk, const float* __restrict__ temp,
    float* __restrict__ A)
{
  const int i  = blockIdx.x;
  const int bh = blockIdx.y;
  const int h  = bh & 7;
  const int t  = threadIdx.x;
  __shared__ float red[128];

  const float nq    = fmaxf(sqrtf(sq[bh * 96 + i]), 1e-12f);
  const float scale = temp[h] / nq;
  float logit = 0.f, val = -1e30f;
  if (t < 96) {
    const float nk = fmaxf(sqrtf(sk[bh * 96 + t]), 1e-12f);
    logit = G[(size_t)bh * 9216 + i * 96 + t] * scale / nk;
    val = logit;
  }
  red[t] = val; __syncthreads();
  #pragma unroll
  for (int o = 64; o > 0; o >>= 1) {
    if (t < o) red[t] = fmaxf(red[t], red[t + o]);
    __syncthreads();
  }
  const float m = red[0]; __syncthreads();
  const float e = (t < 96) ? __expf(logit - m) : 0.f;
  red[t] = e; __syncthreads();
  #pragma unroll
  for (int o = 64; o > 0; o >>= 1) {
    if (t < o) red[t] += red[t + o];
    __syncthreads();
  }
  const float ssum = red[0];
  if (t < 96) A[(size_t)bh * 9216 + i * 96 + t] = e / ssum;
}

// ---------------------------------------------------------------------------
// K5 v2: out = proj( from_blocks( A @ v ) ). One block = 16 attention cols.
// v loaded from column-major layout (coalesced); A@v result kept in regs so
// ao aliases vt -> 49 KB LDS -> 3 blocks/CU. grid (8,128,2), block 256.
// ---------------------------------------------------------------------------
__global__ __launch_bounds__(256) void k5_av_proj(
    const float* __restrict__ vb, const float* __restrict__ A,
    const float* __restrict__ pw, float* __restrict__ out)
{
  const int t  = threadIdx.x;
  const int wg = blockIdx.x, hh = blockIdx.y, b = blockIdx.z;
  const int n0 = hh * 128 + wg * 16;
  __shared__ float smem[12288];   // phase 0-1: vt[h][r][16 nl]; phase 2-3: ao

  // phase 0: load v tile. global: 16 segments of 64B per wave; LDS scatter
  // (16u+nl banks) is 4-way on a handful of insts (negligible).
  #pragma unroll
  for (int it = 0; it < 12; ++it) {
    const int i4  = it * 256 + t;          // [0, 3072)
    const int h   = i4 / 384;
    const int q   = i4 - h * 384;
    const int r4g = q >> 6;
    const int rem = q & 63;
    const int nl  = rem >> 2;
    const int r4  = r4g * 4 + (rem & 3);
    const float4 v = *(const float4*)(vb
        + (size_t)((b * 8 + h) * 16384 + n0 + nl) * 96 + r4 * 4);
    float* dl = smem + (h * 96 + r4 * 4) * 16 + nl;
    dl[0] = v.x; dl[16] = v.y; dl[32] = v.z; dl[48] = v.w;
  }
  __syncthreads();

  // phase 1: A @ v into registers (res). A rows as float4: 4x fewer loads.
  float4 res[6][2];
  #pragma unroll 1
  for (int r = 0; r < 6; ++r) {
    const int task = r * 256 + t;           // h(8) x ip(48) x n4(4)
    const int n4 = task & 3;
    const int ip = (task >> 2) % 48;
    const int h  = task / 192;
    const int i0 = ip * 2;
    const float* arow0 = A + (size_t)((b * 8 + h) * 96 + i0) * 96;
    const float* arow1 = arow0 + 96;
    const float* vp = smem + h * 1536 + n4 * 4;
    float4 a0 = {0, 0, 0, 0}, a1 = {0, 0, 0, 0};
    #pragma unroll 2
    for (int j4 = 0; j4 < 24; ++j4) {
      const float4 w0 = *(const float4*)(arow0 + j4 * 4);
      const float4 w1 = *(const float4*)(arow1 + j4 * 4);
      const float4 v0 = *(const float4*)(vp + (j4 * 4 + 0) * 16);
      const float4 v1 = *(const float4*)(vp + (j4 * 4 + 1) * 16);
      const float4 v2 = *(const float4*)(vp + (j4 * 4 + 2) * 16);
      const float4 v3 = *(const float4*)(vp + (j4 * 4 + 3) * 16);
      a0.x += w0.x * v0.x + w0.y * v1.x + w0.z * v2.x + w0.w * v3.x;
      a0.y += w0.x * v0.y + w0.y * v1.y + w0.z * v2.y + w0.w * v3.y;
      a0.z += w0.x * v0.z + w0.y * v1.z + w0.z * v2.z + w0.w * v3.z;
      a0.w += w0.x * v0.w + w0.y * v1.w + w0.z * v2.w + w0.w * v3.w;
      a1.x += w1.x * v0.x + w1.y * v1.x + w1.z * v2.x + w1.w * v3.x;
      a1.y += w1.x * v0.y + w1.y * v1.y + w1.z * v2.y + w1.w * v3.y;
      a1.z += w1.x * v0.z + w1.y * v1.z + w1.z * v2.z + w1.w * v3.z;
      a1.w += w1.x * v0.w + w1.y * v1.w + w1.z * v2.w + w1.w * v3.w;
    }
    res[r][0] = a0; res[r][1] = a1;
  }
  __syncthreads();   // all vt reads done; smem becomes ao

  // phase 2: write res into ao[ic][p][ww]
  #pragma unroll
  for (int r = 0; r < 6; ++r) {
    const int task = r * 256 + t;
    const int n4 = task & 3;
    const int ip = (task >> 2) % 48;
    const int h  = task / 192;
    const int i0 = ip * 2, i1 = i0 + 1;
    *(float4*)(smem + ((h * 6 + (i0 >> 4)) * 16 + (i0 & 15)) * 16 + n4 * 4) = res[r][0];
    *(float4*)(smem + ((h * 6 + (i1 >> 4)) * 16 + (i1 & 15)) * 16 + n4 * 4) = res[r][1];
  }
  __syncthreads();

  // phase 3: proj 1x1: thread owns one output pixel across 48 channels
  const int xl = t & 63, ph = t >> 6;
  const int p  = ph * 4 + (xl & 3);
  const int wwl = xl >> 2;
  float sv[48];
  #pragma unroll
  for (int ic = 0; ic < 48; ++ic) sv[ic] = smem[(ic * 16 + p) * 16 + wwl];
  const int H = hh * 4 + ph;
  const int Wp = wg * 64 + xl;
  float* outp = out + ((size_t)b * 48 << SHIFT_HW) + (H << 9) + Wp;
  #pragma unroll 1
  for (int oc = 0; oc < 48; oc += 2) {
    float acc0 = 0.f, acc1 = 0.f;
    #pragma unroll
    for (int ic = 0; ic < 48; ++ic) {
      acc0 += pw[oc * 48 + ic]       * sv[ic];   // uniform -> s_loads
      acc1 += pw[(oc + 1) * 48 + ic] * sv[ic];
    }
    outp[(size_t)oc << SHIFT_HW]       = acc0;
    outp[(size_t)(oc + 1) << SHIFT_HW] = acc1;
  }
}

// ---------------------------------------------------------------------------
extern "C" void kernel_launch(void* const* d_in, const int* in_sizes, int n_in,
                              void* d_out, int out_size, void* d_ws, size_t ws_size,
                              hipStream_t stream) {
  const float* x      = (const float*)d_in[0];
  const float* qkv_w  = (const float*)d_in[1];
  const float* dw_w   = (const float*)d_in[2];
  const float* proj_w = (const float*)d_in[3];
  const float* temp   = (const float*)d_in[4];
  float* ws = (float*)d_ws;
  float* qb = ws + QB_OFF;
  float* kb = ws + KB_OFF;
  float* vb = ws + VB_OFF;
  float* G  = ws + G_OFF;
  float* sq = ws + SQ_OFF;
  float* sk = ws + SK_OFF;
  float* A  = ws + A_OFF;

  // zero G + sq + sk (contiguous region); A is fully overwritten by k4
  hipMemsetAsync(G, 0, (size_t)(147456 + 3072) * sizeof(float), stream);

  k1_qkv_dw<<<dim3(32, 32, 2), 384, 0, stream>>>(x, qkv_w, dw_w, qb, kb, vb);
  k3_gram<<<dim3(64, 16), 256, 0, stream>>>(qb, kb, G, sq, sk);
  k4_softmax<<<dim3(96, 16), 128, 0, stream>>>(G, sq, sk, temp, A);
  k5_av_proj<<<dim3(8, 128, 2), 256, 0, stream>>>(vb, A, proj_w, (float*)d_out);
}